// Round 12
// baseline (110.398 us; speedup 1.0000x reference)
//
#include <hip/hip_runtime.h>
#include <hip/hip_bf16.h>

#define NPOS 131072   // 32*64*64 positions per batch

typedef __attribute__((ext_vector_type(8))) short short8;
typedef __attribute__((ext_vector_type(4))) float floatx4;
typedef unsigned int uint32;

__device__ __forceinline__ unsigned short bf16b(float v) {
    __hip_bfloat16 h = __float2bfloat16(v);
    return __builtin_bit_cast(unsigned short, h);
}
// inline-asm pack: ONLY for values destined to LDS/global (never straight to MFMA)
__device__ __forceinline__ uint32 cvtpk(float lo, float hi) {
    uint32 r;
    asm("v_cvt_pk_bf16_f32 %0, %1, %2" : "=v"(r) : "v"(lo), "v"(hi));
    return r;
}
// compiler-visible pack: safe to feed MFMA operands (hazards + scheduling handled)
__device__ __forceinline__ uint32 pk2(float lo, float hi) {
    return (uint32)bf16b(lo) | ((uint32)bf16b(hi) << 16);
}
#if __has_builtin(__builtin_amdgcn_exp2f)
#define EXP2(x) __builtin_amdgcn_exp2f(x)
#else
#define EXP2(x) exp2f(x)
#endif
#if __has_builtin(__builtin_amdgcn_rcpf)
#define RCPF(x) __builtin_amdgcn_rcpf(x)
#else
#define RCPF(x) (1.0f / (x))
#endif

// 16x16x32 operand with logical k=lg*4+e at element slots e=0..3, zeros at e=4..7.
// Both operands of a contraction use the same placement -> exact 16-k dot product.
__device__ __forceinline__ short8 emb4(uint32 w0, uint32 w1) {
    union { uint32 u[4]; short8 s; } z;
    z.u[0] = w0; z.u[1] = w1; z.u[2] = 0; z.u[3] = 0;
    return z.s;
}
__device__ __forceinline__ short8 emb4m(const unsigned short* p) {
    const uint32* q = (const uint32*)p;
    return emb4(q[0], q[1]);
}

// ---------------- K0: wq -> bf16*QS, wout -> bf16 ----------------
__global__ void k_prep_w(const float* __restrict__ wq, const float* __restrict__ wout,
                         unsigned short* __restrict__ wqb, unsigned short* __restrict__ woutb) {
    const float QS = 0.36067376022224085f;   // 0.25 * log2(e)
    int gid = blockIdx.x * 256 + threadIdx.x;
    wqb[gid]   = bf16b(wq[gid] * QS);
    woutb[gid] = bf16b(wout[gid]);
}

// ---------------- K1: wkv[oc][ic][term] f32 -> wtb[ic][oc][term] bf16 ----------------
__global__ void k_prep_wkvb(const float* __restrict__ wkv, unsigned short* __restrict__ wtb) {
    int gid = blockIdx.x * 256 + threadIdx.x;
    int ic = gid >> 14;
    int oc = (gid >> 7) & 127;
    float4 v = *(const float4*)(wkv + ((size_t)(oc * 64 + ic)) * 512 + (size_t)(gid & 127) * 4);
    uint32* dst = (uint32*)(wtb + (size_t)gid * 4);
    dst[0] = cvtpk(v.x, v.y);
    dst[1] = cvtpk(v.z, v.w);
}

// ---------------- K2: conv as bf16 MFMA GEMM, split-K over ic (unchanged, passing) ----------------
__global__ __launch_bounds__(256) void k_conv_mfma(const float* __restrict__ x,
                                                   const unsigned short* __restrict__ wtb,
                                                   float* __restrict__ partial) {
    __shared__ __align__(16) unsigned short As[64 * 72];
    __shared__ __align__(16) unsigned short Bs[128 * 72];
    const int bid = blockIdx.x;
    const int ic = bid & 63;
    const int b  = (bid >> 6) & 1;
    const int pz = bid >> 7;
    const int tid = threadIdx.x;
    const int lane = tid & 63, wv = tid >> 6;
    const int lc = lane & 15, lg = lane >> 4;

    floatx4 acc[4][2];
#pragma unroll
    for (int mt = 0; mt < 4; ++mt)
#pragma unroll
        for (int n = 0; n < 2; ++n) acc[mt][n] = {0.f, 0.f, 0.f, 0.f};

    const float* xp = x + ((size_t)b * 64 + ic) * NPOS + (size_t)pz * 8 * 4096;
    const unsigned short* wp = wtb + (size_t)ic * 128 * 512;

    for (int rz = 0; rz < 8; ++rz) {
        __syncthreads();
        const float* plane = xp + (size_t)rz * 4096;
#pragma unroll
        for (int t2 = 0; t2 < 4; ++t2) {
            int e = (t2 * 256 + tid) * 4;
            int y = e >> 6, x0 = e & 63;
            int p = ((y >> 3) << 3) + (x0 >> 3);
            int k = ((y & 7) << 3) + (x0 & 7);
            float4 v = *(const float4*)(plane + e);
            uint32* dst = (uint32*)&As[p * 72 + k];
            dst[0] = cvtpk(v.x, v.y);
            dst[1] = cvtpk(v.z, v.w);
        }
        {
            int oc = tid >> 1, hf = tid & 1;
            const uint4* src = (const uint4*)(wp + (size_t)oc * 512 + rz * 64 + hf * 32);
            uint4* dst = (uint4*)&Bs[oc * 72 + hf * 32];
#pragma unroll
            for (int r = 0; r < 4; ++r) dst[r] = src[r];
        }
        __syncthreads();
#pragma unroll
        for (int ks = 0; ks < 2; ++ks) {
            short8 bb0 = *(const short8*)&Bs[((wv * 2 + 0) * 16 + lc) * 72 + ks * 32 + lg * 8];
            short8 bb1 = *(const short8*)&Bs[((wv * 2 + 1) * 16 + lc) * 72 + ks * 32 + lg * 8];
#pragma unroll
            for (int mt = 0; mt < 4; ++mt) {
                short8 a = *(const short8*)&As[(mt * 16 + lc) * 72 + ks * 32 + lg * 8];
                acc[mt][0] = __builtin_amdgcn_mfma_f32_16x16x32_bf16(a, bb0, acc[mt][0], 0, 0, 0);
                acc[mt][1] = __builtin_amdgcn_mfma_f32_16x16x32_bf16(a, bb1, acc[mt][1], 0, 0, 0);
            }
        }
    }
    float* pb = partial + (((size_t)ic * 2 + b) * 256 + pz * 64) * 128;
#pragma unroll
    for (int mt = 0; mt < 4; ++mt)
#pragma unroll
        for (int ntl = 0; ntl < 2; ++ntl) {
            int oc = (wv * 2 + ntl) * 16 + lc;
#pragma unroll
            for (int r = 0; r < 4; ++r) {
                int m = mt * 16 + lg * 4 + r;
                pb[(size_t)m * 128 + oc] = acc[mt][ntl][r];
            }
        }
}

// ---------------- K3: reduce over ic; K -> bf16 [b][h][256][16], V -> bf16 [b][h][16][256] ----------------
__global__ void k_reduce(const float* __restrict__ partial,
                         unsigned short* __restrict__ kt, unsigned short* __restrict__ vt) {
    int gid = blockIdx.x * 256 + threadIdx.x;
    int oc = gid & 127;
    int bp = gid >> 7;          // b*256 + j
    int b = bp >> 8;
    int j = bp & 255;
    const float* p = partial + (size_t)bp * 128 + oc;
    float s = 0.f;
#pragma unroll 8
    for (int ic = 0; ic < 64; ++ic) s += p[(size_t)ic * 65536];
    int h = (oc & 63) >> 4, i = oc & 15;
    if (oc < 64)
        kt[(((size_t)b * 4 + h) * 256 + j) * 16 + i] = bf16b(s);
    else
        vt[(((size_t)b * 4 + h) * 16 + i) * 256 + j] = bf16b(s);
}

// ---------------- K4: round-8 structure + register-P head loop (compiler-visible packs) ----------------
// grid 4096 = b(2) x 2048 n-blocks of 64; 256 thr; wave wv = head wv, 64 queries/wave.
__global__ __launch_bounds__(256, 5) void k_attn8(
    const float* __restrict__ x, const unsigned short* __restrict__ wqb,
    const unsigned short* __restrict__ woutb, const unsigned short* __restrict__ kt,
    const unsigned short* __restrict__ vt, float* __restrict__ out)
{
    __shared__ __align__(16) unsigned short s_at[64 * 72];    // x^T then att [n][c]
    __shared__ __align__(16) unsigned short s_q[4][64 * 34];  // per-wave Q [n][i] stride 34; later yb f32 [64][68]
    __shared__ float s_l[4][64];

    const int tid = threadIdx.x;
    const int b = blockIdx.x >> 11;
    const int n_base = (blockIdx.x & 2047) << 6;
    const int lane = tid & 63;
    const int wv = tid >> 6;     // head index
    const int lc = lane & 15;
    const int lg = lane >> 4;

    unsigned short* qs = s_q[wv];

    // ---- stage x^T [64][72] cooperatively (round-8 verbatim) ----
    {
        int n_l = tid & 63;
        int c0  = (tid >> 6) * 16;
        const float* xb = x + ((size_t)b << 23) + n_base + n_l;
        uint32* xrow = (uint32*)&s_at[n_l * 72 + c0];
#pragma unroll
        for (int r = 0; r < 8; ++r) {
            float v0 = xb[(size_t)(c0 + 2 * r) << 17];
            float v1 = xb[(size_t)(c0 + 2 * r + 1) << 17];
            xrow[r] = cvtpk(v0, v1);
        }
    }
    __syncthreads();   // B1: x^T staged

    // ---- Q-proj (round-8 verbatim, store stride 34) ----
#pragma unroll
    for (int t = 0; t < 4; ++t) {
        floatx4 c = {0.f, 0.f, 0.f, 0.f};
#pragma unroll
        for (int ks = 0; ks < 2; ++ks) {
            short8 a  = *(const short8*)&s_at[(t * 16 + lc) * 72 + ks * 32 + lg * 8];
            short8 bb = *(const short8*)(wqb + (wv * 16 + lc) * 64 + ks * 32 + lg * 8);
            c = __builtin_amdgcn_mfma_f32_16x16x32_bf16(a, bb, c, 0, 0, 0);
        }
#pragma unroll
        for (int r = 0; r < 4; ++r)
            qs[(t * 16 + lg * 4 + r) * 34 + lc] = bf16b(c[r]);
    }
    // ---- hoist Q B-frags: logical k=i=lg*4+e via emb4 (memory-fed) ----
    short8 qf[4];
#pragma unroll
    for (int t = 0; t < 4; ++t)
        qf[t] = emb4m(&qs[(t * 16 + lc) * 34 + lg * 4]);

    __syncthreads();   // B2: all Q-proj s_at reads done (att overwrites s_at later)

    // ---- head loop: 16 j-tiles of 16 keys, all-register P (compiler-visible packs) ----
    const unsigned short* kh = kt + (((size_t)b * 4 + wv) << 12);
    const unsigned short* vh = vt + (((size_t)b * 4 + wv) << 12);
    float lp[4] = {0.f, 0.f, 0.f, 0.f};
    floatx4 pv[4];
#pragma unroll
    for (int t = 0; t < 4; ++t) pv[t] = {0.f, 0.f, 0.f, 0.f};

#pragma unroll 4
    for (int jt = 0; jt < 16; ++jt) {
        const int j0 = jt * 16;
        // K A-frag: row=j=lc, logical k=i=lg*4+e ; V B-frag: col=i=lc, logical k=j_local=lg*4+e
        short8 kf = emb4m(kh + (size_t)(j0 + lc) * 16 + lg * 4);
        short8 vf = emb4m(vh + (size_t)lc * 256 + j0 + lg * 4);
#pragma unroll
        for (int t = 0; t < 4; ++t) {
            floatx4 z = {0.f, 0.f, 0.f, 0.f};
            floatx4 c = __builtin_amdgcn_mfma_f32_16x16x32_bf16(kf, qf[t], z, 0, 0, 0); // S^T: n=lc, j=lg*4+r
            float p0 = EXP2(c[0]), p1 = EXP2(c[1]), p2 = EXP2(c[2]), p3 = EXP2(c[3]);
            lp[t] += (p0 + p1) + (p2 + p3);
            short8 pa = emb4(pk2(p0, p1), pk2(p2, p3));       // P A-frag: row=n=lc, logical k=j=lg*4+e
            pv[t] = __builtin_amdgcn_mfma_f32_16x16x32_bf16(pa, vf, pv[t], 0, 0, 0);    // att: i=lc, n=lg*4+r
        }
    }

    // ---- denominators via s_l (round-8 verbatim), rescale, att -> s_at ----
#pragma unroll
    for (int t = 0; t < 4; ++t) {
        lp[t] += __shfl_xor(lp[t], 16, 64);
        lp[t] += __shfl_xor(lp[t], 32, 64);
    }
    if (lane < 16) {
#pragma unroll
        for (int t = 0; t < 4; ++t) s_l[wv][t * 16 + lane] = lp[t];
    }
#pragma unroll
    for (int t = 0; t < 4; ++t) {
#pragma unroll
        for (int r = 0; r < 4; ++r) {
            float rl = RCPF(s_l[wv][t * 16 + lg * 4 + r]);
            s_at[(t * 16 + lg * 4 + r) * 72 + wv * 16 + lc] = bf16b(pv[t][r] * rl);
        }
    }

    __syncthreads();   // B3: att complete, all waves done with s_q (qf hoisted before B2)

    // ---- out-proj (round-8 verbatim); yb aliases s_q ----
    float* yb = (float*)&s_q[0][0];   // [64][68] f32 = 17408 B = sizeof(s_q)
#pragma unroll
    for (int t = 0; t < 4; ++t) {
        floatx4 c = {0.f, 0.f, 0.f, 0.f};
#pragma unroll
        for (int ks = 0; ks < 2; ++ks) {
            short8 a  = *(const short8*)&s_at[(t * 16 + lc) * 72 + ks * 32 + lg * 8];
            short8 bb = *(const short8*)(woutb + (wv * 16 + lc) * 64 + ks * 32 + lg * 8);
            c = __builtin_amdgcn_mfma_f32_16x16x32_bf16(a, bb, c, 0, 0, 0);
        }
#pragma unroll
        for (int r = 0; r < 4; ++r)
            yb[(wv * 16 + lc) * 68 + t * 16 + lg * 4 + r] = c[r];
    }
    __syncthreads();   // B4

    // ---- coalesced copyout (round-8 verbatim) ----
    {
        int o = tid >> 2, nc = (tid & 3) * 16;
        float* dst = out + ((size_t)b << 23) + (size_t)o * 131072 + n_base + nc;
        const float* src = yb + o * 68 + nc;
#pragma unroll
        for (int i = 0; i < 4; ++i)
            *(float4*)(dst + i * 4) = *(const float4*)(src + i * 4);
    }
}

extern "C" void kernel_launch(void* const* d_in, const int* in_sizes, int n_in,
                              void* d_out, int out_size, void* d_ws, size_t ws_size,
                              hipStream_t stream) {
    const float* x    = (const float*)d_in[0];
    const float* wq   = (const float*)d_in[1];
    const float* wkv  = (const float*)d_in[2];
    const float* wout = (const float*)d_in[3];
    float* out = (float*)d_out;
    float* ws = (float*)d_ws;

    unsigned short* wtb = (unsigned short*)ws;              // [64][128][512] bf16 = 8 MB
    float* partial = ws + 2097152;                          // [64][2][256][128] f32 = 16 MB
    unsigned short* ktu = (unsigned short*)(ws + 6291456);  // [2][4][256][16] bf16
    unsigned short* vtu   = ktu + 32768;                    // [2][4][16][256] bf16
    unsigned short* wqb   = vtu + 32768;                    // [64][64] bf16
    unsigned short* woutb = wqb + 4096;                     // [64][64] bf16

    k_prep_w   <<<16,   256, 0, stream>>>(wq, wout, wqb, woutb);
    k_prep_wkvb<<<4096, 256, 0, stream>>>(wkv, wtb);
    k_conv_mfma<<<512,  256, 0, stream>>>(x, wtb, partial);
    k_reduce   <<<256,  256, 0, stream>>>(partial, ktu, vtu);
    k_attn8    <<<4096, 256, 0, stream>>>(x, wqb, woutb, ktu, vtu, out);
}

// Round 15
// 105.172 us; speedup vs baseline: 1.0497x; 1.0497x over previous
//
#include <hip/hip_runtime.h>
#include <hip/hip_bf16.h>

#define NPOS 131072   // 32*64*64 positions per batch

typedef __attribute__((ext_vector_type(8))) short short8;
typedef __attribute__((ext_vector_type(4))) float floatx4;
typedef unsigned int uint32;

__device__ __forceinline__ unsigned short bf16b(float v) {
    __hip_bfloat16 h = __float2bfloat16(v);
    return __builtin_bit_cast(unsigned short, h);
}
// inline-asm pack: ONLY for values destined to LDS/global (never straight to MFMA)
__device__ __forceinline__ uint32 cvtpk(float lo, float hi) {
    uint32 r;
    asm("v_cvt_pk_bf16_f32 %0, %1, %2" : "=v"(r) : "v"(lo), "v"(hi));
    return r;
}
// compiler-visible pack: safe to feed MFMA operands (hazards + scheduling handled)
__device__ __forceinline__ uint32 pk2(float lo, float hi) {
    return (uint32)bf16b(lo) | ((uint32)bf16b(hi) << 16);
}
#if __has_builtin(__builtin_amdgcn_exp2f)
#define EXP2(x) __builtin_amdgcn_exp2f(x)
#else
#define EXP2(x) exp2f(x)
#endif
#if __has_builtin(__builtin_amdgcn_rcpf)
#define RCPF(x) __builtin_amdgcn_rcpf(x)
#else
#define RCPF(x) (1.0f / (x))
#endif

// 16x16x32 operand with logical k=lg*4+e at element slots e=0..3, zeros at e=4..7.
__device__ __forceinline__ short8 emb4(uint32 w0, uint32 w1) {
    union { uint32 u[4]; short8 s; } z;
    z.u[0] = w0; z.u[1] = w1; z.u[2] = 0; z.u[3] = 0;
    return z.s;
}
__device__ __forceinline__ short8 emb4m(const unsigned short* p) {
    const uint32* q = (const uint32*)p;
    return emb4(q[0], q[1]);
}

// ---------------- K0: wq -> bf16*QS, wout -> bf16 ----------------
__global__ void k_prep_w(const float* __restrict__ wq, const float* __restrict__ wout,
                         unsigned short* __restrict__ wqb, unsigned short* __restrict__ woutb) {
    const float QS = 0.36067376022224085f;   // 0.25 * log2(e)
    int gid = blockIdx.x * 256 + threadIdx.x;
    wqb[gid]   = bf16b(wq[gid] * QS);
    woutb[gid] = bf16b(wout[gid]);
}

// ---------------- K1: wkv[oc][ic][term] f32 -> wtb[ic][oc][term] bf16 ----------------
__global__ void k_prep_wkvb(const float* __restrict__ wkv, unsigned short* __restrict__ wtb) {
    int gid = blockIdx.x * 256 + threadIdx.x;
    int ic = gid >> 14;
    int oc = (gid >> 7) & 127;
    float4 v = *(const float4*)(wkv + ((size_t)(oc * 64 + ic)) * 512 + (size_t)(gid & 127) * 4);
    uint32* dst = (uint32*)(wtb + (size_t)gid * 4);
    dst[0] = cvtpk(v.x, v.y);
    dst[1] = cvtpk(v.z, v.w);
}

// ---------------- K2: conv as bf16 MFMA GEMM, split-K over ic (R12-exact, passing) ----------------
__global__ __launch_bounds__(256) void k_conv_mfma(const float* __restrict__ x,
                                                   const unsigned short* __restrict__ wtb,
                                                   float* __restrict__ partial) {
    __shared__ __align__(16) unsigned short As[64 * 72];
    __shared__ __align__(16) unsigned short Bs[128 * 72];
    const int bid = blockIdx.x;
    const int ic = bid & 63;
    const int b  = (bid >> 6) & 1;
    const int pz = bid >> 7;
    const int tid = threadIdx.x;
    const int lane = tid & 63, wv = tid >> 6;
    const int lc = lane & 15, lg = lane >> 4;

    floatx4 acc[4][2];
#pragma unroll
    for (int mt = 0; mt < 4; ++mt)
#pragma unroll
        for (int n = 0; n < 2; ++n) acc[mt][n] = {0.f, 0.f, 0.f, 0.f};

    const float* xp = x + ((size_t)b * 64 + ic) * NPOS + (size_t)pz * 8 * 4096;
    const unsigned short* wp = wtb + (size_t)ic * 128 * 512;

    for (int rz = 0; rz < 8; ++rz) {
        __syncthreads();
        const float* plane = xp + (size_t)rz * 4096;
#pragma unroll
        for (int t2 = 0; t2 < 4; ++t2) {
            int e = (t2 * 256 + tid) * 4;
            int y = e >> 6, x0 = e & 63;
            int p = ((y >> 3) << 3) + (x0 >> 3);
            int k = ((y & 7) << 3) + (x0 & 7);
            float4 v = *(const float4*)(plane + e);
            uint32* dst = (uint32*)&As[p * 72 + k];
            dst[0] = cvtpk(v.x, v.y);
            dst[1] = cvtpk(v.z, v.w);
        }
        {
            int oc = tid >> 1, hf = tid & 1;
            const uint4* src = (const uint4*)(wp + (size_t)oc * 512 + rz * 64 + hf * 32);
            uint4* dst = (uint4*)&Bs[oc * 72 + hf * 32];
#pragma unroll
            for (int r = 0; r < 4; ++r) dst[r] = src[r];
        }
        __syncthreads();
#pragma unroll
        for (int ks = 0; ks < 2; ++ks) {
            short8 bb0 = *(const short8*)&Bs[((wv * 2 + 0) * 16 + lc) * 72 + ks * 32 + lg * 8];
            short8 bb1 = *(const short8*)&Bs[((wv * 2 + 1) * 16 + lc) * 72 + ks * 32 + lg * 8];
#pragma unroll
            for (int mt = 0; mt < 4; ++mt) {
                short8 a = *(const short8*)&As[(mt * 16 + lc) * 72 + ks * 32 + lg * 8];
                acc[mt][0] = __builtin_amdgcn_mfma_f32_16x16x32_bf16(a, bb0, acc[mt][0], 0, 0, 0);
                acc[mt][1] = __builtin_amdgcn_mfma_f32_16x16x32_bf16(a, bb1, acc[mt][1], 0, 0, 0);
            }
        }
    }
    float* pb = partial + (((size_t)ic * 2 + b) * 256 + pz * 64) * 128;
#pragma unroll
    for (int mt = 0; mt < 4; ++mt)
#pragma unroll
        for (int ntl = 0; ntl < 2; ++ntl) {
            int oc = (wv * 2 + ntl) * 16 + lc;
#pragma unroll
            for (int r = 0; r < 4; ++r) {
                int m = mt * 16 + lg * 4 + r;
                pb[(size_t)m * 128 + oc] = acc[mt][ntl][r];
            }
        }
}

// ---------------- K3: reduce over ic; K -> bf16 [b][h][256][16], V -> bf16 [b][h][16][256] ----------------
__global__ void k_reduce(const float* __restrict__ partial,
                         unsigned short* __restrict__ kt, unsigned short* __restrict__ vt) {
    int gid = blockIdx.x * 256 + threadIdx.x;
    int oc = gid & 127;
    int bp = gid >> 7;          // b*256 + j
    int b = bp >> 8;
    int j = bp & 255;
    const float* p = partial + (size_t)bp * 128 + oc;
    float s = 0.f;
#pragma unroll 8
    for (int ic = 0; ic < 64; ++ic) s += p[(size_t)ic * 65536];
    int h = (oc & 63) >> 4, i = oc & 15;
    if (oc < 64)
        kt[(((size_t)b * 4 + h) * 256 + j) * 16 + i] = bf16b(s);
    else
        vt[(((size_t)b * 4 + h) * 16 + i) * 256 + j] = bf16b(s);
}

// ---------------- K4: R12 verbatim EXCEPT epilogue = direct stores (single-variable bisect) ----------------
// grid 4096 = b(2) x 2048 n-blocks of 64; 256 thr; wave wv = head wv, 64 queries/wave.
__global__ __launch_bounds__(256, 5) void k_attn11(
    const float* __restrict__ x, const unsigned short* __restrict__ wqb,
    const unsigned short* __restrict__ woutb, const unsigned short* __restrict__ kt,
    const unsigned short* __restrict__ vt, float* __restrict__ out)
{
    __shared__ __align__(16) unsigned short s_at[64 * 72];    // x^T then att [n][c]
    __shared__ __align__(16) unsigned short s_q[4][64 * 34];  // per-wave Q [n][i] stride 34 (R12-exact)
    __shared__ float s_l[4][64];

    const int tid = threadIdx.x;
    const int b = blockIdx.x >> 11;
    const int n_base = (blockIdx.x & 2047) << 6;
    const int lane = tid & 63;
    const int wv = tid >> 6;     // head index
    const int lc = lane & 15;
    const int lg = lane >> 4;

    unsigned short* qs = s_q[wv];

    // ---- stage x^T [64][72] cooperatively (R12 verbatim) ----
    {
        int n_l = tid & 63;
        int c0  = (tid >> 6) * 16;
        const float* xb = x + ((size_t)b << 23) + n_base + n_l;
        uint32* xrow = (uint32*)&s_at[n_l * 72 + c0];
#pragma unroll
        for (int r = 0; r < 8; ++r) {
            float v0 = xb[(size_t)(c0 + 2 * r) << 17];
            float v1 = xb[(size_t)(c0 + 2 * r + 1) << 17];
            xrow[r] = cvtpk(v0, v1);
        }
    }
    __syncthreads();   // B1: x^T staged

    // ---- Q-proj (R12 verbatim, store stride 34) ----
#pragma unroll
    for (int t = 0; t < 4; ++t) {
        floatx4 c = {0.f, 0.f, 0.f, 0.f};
#pragma unroll
        for (int ks = 0; ks < 2; ++ks) {
            short8 a  = *(const short8*)&s_at[(t * 16 + lc) * 72 + ks * 32 + lg * 8];
            short8 bb = *(const short8*)(wqb + (wv * 16 + lc) * 64 + ks * 32 + lg * 8);
            c = __builtin_amdgcn_mfma_f32_16x16x32_bf16(a, bb, c, 0, 0, 0);
        }
#pragma unroll
        for (int r = 0; r < 4; ++r)
            qs[(t * 16 + lg * 4 + r) * 34 + lc] = bf16b(c[r]);
    }
    // ---- hoist Q B-frags: logical k=i=lg*4+e via emb4 (memory-fed, R12 verbatim) ----
    short8 qf[4];
#pragma unroll
    for (int t = 0; t < 4; ++t)
        qf[t] = emb4m(&qs[(t * 16 + lc) * 34 + lg * 4]);

    __syncthreads();   // B2: all Q-proj s_at reads done (att overwrites s_at later)

    // ---- head loop: 16 j-tiles of 16 keys, all-register P (R12 verbatim) ----
    const unsigned short* kh = kt + (((size_t)b * 4 + wv) << 12);
    const unsigned short* vh = vt + (((size_t)b * 4 + wv) << 12);
    float lp[4] = {0.f, 0.f, 0.f, 0.f};
    floatx4 pv[4];
#pragma unroll
    for (int t = 0; t < 4; ++t) pv[t] = {0.f, 0.f, 0.f, 0.f};

#pragma unroll 4
    for (int jt = 0; jt < 16; ++jt) {
        const int j0 = jt * 16;
        short8 kf = emb4m(kh + (size_t)(j0 + lc) * 16 + lg * 4);
        short8 vf = emb4m(vh + (size_t)lc * 256 + j0 + lg * 4);
#pragma unroll
        for (int t = 0; t < 4; ++t) {
            floatx4 z = {0.f, 0.f, 0.f, 0.f};
            floatx4 c = __builtin_amdgcn_mfma_f32_16x16x32_bf16(kf, qf[t], z, 0, 0, 0); // S^T: n=lc, j=lg*4+r
            float p0 = EXP2(c[0]), p1 = EXP2(c[1]), p2 = EXP2(c[2]), p3 = EXP2(c[3]);
            lp[t] += (p0 + p1) + (p2 + p3);
            short8 pa = emb4(pk2(p0, p1), pk2(p2, p3));       // P: row=n=lc, logical k=j=lg*4+e
            pv[t] = __builtin_amdgcn_mfma_f32_16x16x32_bf16(pa, vf, pv[t], 0, 0, 0);    // att: i=lc, n=lg*4+r
        }
    }

    // ---- denominators via s_l (R12 verbatim), rescale, att -> s_at ----
#pragma unroll
    for (int t = 0; t < 4; ++t) {
        lp[t] += __shfl_xor(lp[t], 16, 64);
        lp[t] += __shfl_xor(lp[t], 32, 64);
    }
    if (lane < 16) {
#pragma unroll
        for (int t = 0; t < 4; ++t) s_l[wv][t * 16 + lane] = lp[t];
    }
#pragma unroll
    for (int t = 0; t < 4; ++t) {
#pragma unroll
        for (int r = 0; r < 4; ++r) {
            float rl = RCPF(s_l[wv][t * 16 + lg * 4 + r]);
            s_at[(t * 16 + lg * 4 + r) * 72 + wv * 16 + lc] = bf16b(pv[t][r] * rl);
        }
    }

    __syncthreads();   // B3: att complete

    // ---- out-proj + DIRECT float4 stores (the ONE change vs R12):
    //      o = wv*16+lc (C col), n = n_base + t*16 + lg*4 + r (C row) ----
#pragma unroll
    for (int t = 0; t < 4; ++t) {
        floatx4 c = {0.f, 0.f, 0.f, 0.f};
#pragma unroll
        for (int ks = 0; ks < 2; ++ks) {
            short8 a  = *(const short8*)&s_at[(t * 16 + lc) * 72 + ks * 32 + lg * 8];
            short8 bb = *(const short8*)(woutb + (wv * 16 + lc) * 64 + ks * 32 + lg * 8);
            c = __builtin_amdgcn_mfma_f32_16x16x32_bf16(a, bb, c, 0, 0, 0);
        }
        float* dst = out + ((size_t)b << 23) + (size_t)(wv * 16 + lc) * NPOS
                   + n_base + t * 16 + lg * 4;
        *(floatx4*)dst = c;
    }
}

extern "C" void kernel_launch(void* const* d_in, const int* in_sizes, int n_in,
                              void* d_out, int out_size, void* d_ws, size_t ws_size,
                              hipStream_t stream) {
    const float* x    = (const float*)d_in[0];
    const float* wq   = (const float*)d_in[1];
    const float* wkv  = (const float*)d_in[2];
    const float* wout = (const float*)d_in[3];
    float* out = (float*)d_out;
    float* ws = (float*)d_ws;

    unsigned short* wtb = (unsigned short*)ws;              // [64][128][512] bf16 = 8 MB
    float* partial = ws + 2097152;                          // [64][2][256][128] f32 = 16 MB
    unsigned short* ktu = (unsigned short*)(ws + 6291456);  // [2][4][256][16] bf16
    unsigned short* vtu   = ktu + 32768;                    // [2][4][16][256] bf16
    unsigned short* wqb   = vtu + 32768;                    // [64][64] bf16
    unsigned short* woutb = wqb + 4096;                     // [64][64] bf16

    k_prep_w   <<<16,   256, 0, stream>>>(wq, wout, wqb, woutb);
    k_prep_wkvb<<<4096, 256, 0, stream>>>(wkv, wtb);
    k_conv_mfma<<<512,  256, 0, stream>>>(x, wtb, partial);
    k_reduce   <<<256,  256, 0, stream>>>(partial, ktu, vtu);
    k_attn11   <<<4096, 256, 0, stream>>>(x, wqb, woutb, ktu, vtu, out);
}

// Round 16
// 100.842 us; speedup vs baseline: 1.0948x; 1.0429x over previous
//
#include <hip/hip_runtime.h>
#include <hip/hip_bf16.h>

#define NPOS 131072   // 32*64*64 positions per batch

typedef __attribute__((ext_vector_type(8))) short short8;
typedef __attribute__((ext_vector_type(4))) float floatx4;
typedef unsigned int uint32;

__device__ __forceinline__ unsigned short bf16b(float v) {
    __hip_bfloat16 h = __float2bfloat16(v);
    return __builtin_bit_cast(unsigned short, h);
}
// inline-asm pack: ONLY for values destined to LDS/global (never straight to MFMA)
__device__ __forceinline__ uint32 cvtpk(float lo, float hi) {
    uint32 r;
    asm("v_cvt_pk_bf16_f32 %0, %1, %2" : "=v"(r) : "v"(lo), "v"(hi));
    return r;
}
// compiler-visible pack: safe to feed MFMA operands (hazards + scheduling handled)
__device__ __forceinline__ uint32 pk2(float lo, float hi) {
    return (uint32)bf16b(lo) | ((uint32)bf16b(hi) << 16);
}
#if __has_builtin(__builtin_amdgcn_exp2f)
#define EXP2(x) __builtin_amdgcn_exp2f(x)
#else
#define EXP2(x) exp2f(x)
#endif
#if __has_builtin(__builtin_amdgcn_rcpf)
#define RCPF(x) __builtin_amdgcn_rcpf(x)
#else
#define RCPF(x) (1.0f / (x))
#endif

// 16x16x32 operand with logical k=lg*4+e at element slots e=0..3, zeros at e=4..7.
__device__ __forceinline__ short8 emb4(uint32 w0, uint32 w1) {
    union { uint32 u[4]; short8 s; } z;
    z.u[0] = w0; z.u[1] = w1; z.u[2] = 0; z.u[3] = 0;
    return z.s;
}
__device__ __forceinline__ short8 emb4m(const unsigned short* p) {
    const uint32* q = (const uint32*)p;
    return emb4(q[0], q[1]);
}

// ---------------- K0: wq -> bf16*QS, wout -> bf16 ----------------
__global__ void k_prep_w(const float* __restrict__ wq, const float* __restrict__ wout,
                         unsigned short* __restrict__ wqb, unsigned short* __restrict__ woutb) {
    const float QS = 0.36067376022224085f;   // 0.25 * log2(e)
    int gid = blockIdx.x * 256 + threadIdx.x;
    wqb[gid]   = bf16b(wq[gid] * QS);
    woutb[gid] = bf16b(wout[gid]);
}

// ---------------- K1: wkv[oc][ic][term] f32 -> wtb[ic][oc][term] bf16 ----------------
__global__ void k_prep_wkvb(const float* __restrict__ wkv, unsigned short* __restrict__ wtb) {
    int gid = blockIdx.x * 256 + threadIdx.x;
    int ic = gid >> 14;
    int oc = (gid >> 7) & 127;
    float4 v = *(const float4*)(wkv + ((size_t)(oc * 64 + ic)) * 512 + (size_t)(gid & 127) * 4);
    uint32* dst = (uint32*)(wtb + (size_t)gid * 4);
    dst[0] = cvtpk(v.x, v.y);
    dst[1] = cvtpk(v.z, v.w);
}

// ---------------- K2: conv as bf16 MFMA GEMM, split-K over ic (R12-exact, passing) ----------------
__global__ __launch_bounds__(256) void k_conv_mfma(const float* __restrict__ x,
                                                   const unsigned short* __restrict__ wtb,
                                                   float* __restrict__ partial) {
    __shared__ __align__(16) unsigned short As[64 * 72];
    __shared__ __align__(16) unsigned short Bs[128 * 72];
    const int bid = blockIdx.x;
    const int ic = bid & 63;
    const int b  = (bid >> 6) & 1;
    const int pz = bid >> 7;
    const int tid = threadIdx.x;
    const int lane = tid & 63, wv = tid >> 6;
    const int lc = lane & 15, lg = lane >> 4;

    floatx4 acc[4][2];
#pragma unroll
    for (int mt = 0; mt < 4; ++mt)
#pragma unroll
        for (int n = 0; n < 2; ++n) acc[mt][n] = {0.f, 0.f, 0.f, 0.f};

    const float* xp = x + ((size_t)b * 64 + ic) * NPOS + (size_t)pz * 8 * 4096;
    const unsigned short* wp = wtb + (size_t)ic * 128 * 512;

    for (int rz = 0; rz < 8; ++rz) {
        __syncthreads();
        const float* plane = xp + (size_t)rz * 4096;
#pragma unroll
        for (int t2 = 0; t2 < 4; ++t2) {
            int e = (t2 * 256 + tid) * 4;
            int y = e >> 6, x0 = e & 63;
            int p = ((y >> 3) << 3) + (x0 >> 3);
            int k = ((y & 7) << 3) + (x0 & 7);
            float4 v = *(const float4*)(plane + e);
            uint32* dst = (uint32*)&As[p * 72 + k];
            dst[0] = cvtpk(v.x, v.y);
            dst[1] = cvtpk(v.z, v.w);
        }
        {
            int oc = tid >> 1, hf = tid & 1;
            const uint4* src = (const uint4*)(wp + (size_t)oc * 512 + rz * 64 + hf * 32);
            uint4* dst = (uint4*)&Bs[oc * 72 + hf * 32];
#pragma unroll
            for (int r = 0; r < 4; ++r) dst[r] = src[r];
        }
        __syncthreads();
#pragma unroll
        for (int ks = 0; ks < 2; ++ks) {
            short8 bb0 = *(const short8*)&Bs[((wv * 2 + 0) * 16 + lc) * 72 + ks * 32 + lg * 8];
            short8 bb1 = *(const short8*)&Bs[((wv * 2 + 1) * 16 + lc) * 72 + ks * 32 + lg * 8];
#pragma unroll
            for (int mt = 0; mt < 4; ++mt) {
                short8 a = *(const short8*)&As[(mt * 16 + lc) * 72 + ks * 32 + lg * 8];
                acc[mt][0] = __builtin_amdgcn_mfma_f32_16x16x32_bf16(a, bb0, acc[mt][0], 0, 0, 0);
                acc[mt][1] = __builtin_amdgcn_mfma_f32_16x16x32_bf16(a, bb1, acc[mt][1], 0, 0, 0);
            }
        }
    }
    float* pb = partial + (((size_t)ic * 2 + b) * 256 + pz * 64) * 128;
#pragma unroll
    for (int mt = 0; mt < 4; ++mt)
#pragma unroll
        for (int ntl = 0; ntl < 2; ++ntl) {
            int oc = (wv * 2 + ntl) * 16 + lc;
#pragma unroll
            for (int r = 0; r < 4; ++r) {
                int m = mt * 16 + lg * 4 + r;
                pb[(size_t)m * 128 + oc] = acc[mt][ntl][r];
            }
        }
}

// ---------------- K3: reduce over ic; K -> bf16 [b][h][256][16], V -> bf16 [b][h][16][256] ----------------
__global__ void k_reduce(const float* __restrict__ partial,
                         unsigned short* __restrict__ kt, unsigned short* __restrict__ vt) {
    int gid = blockIdx.x * 256 + threadIdx.x;
    int oc = gid & 127;
    int bp = gid >> 7;          // b*256 + j
    int b = bp >> 8;
    int j = bp & 255;
    const float* p = partial + (size_t)bp * 128 + oc;
    float s = 0.f;
#pragma unroll 8
    for (int ic = 0; ic < 64; ++ic) s += p[(size_t)ic * 65536];
    int h = (oc & 63) >> 4, i = oc & 15;
    if (oc < 64)
        kt[(((size_t)b * 4 + h) * 256 + j) * 16 + i] = bf16b(s);
    else
        vt[(((size_t)b * 4 + h) * 16 + i) * 256 + j] = bf16b(s);
}

// ---------------- K4: R15 verbatim EXCEPT s_q stride 34 -> 26 (LDS 23552, 6 blocks/CU) ----------------
// grid 4096 = b(2) x 2048 n-blocks of 64; 256 thr; wave wv = head wv, 64 queries/wave.
__global__ __launch_bounds__(256, 5) void k_attn12(
    const float* __restrict__ x, const unsigned short* __restrict__ wqb,
    const unsigned short* __restrict__ woutb, const unsigned short* __restrict__ kt,
    const unsigned short* __restrict__ vt, float* __restrict__ out)
{
    __shared__ __align__(16) unsigned short s_at[64 * 72];    // x^T then att [n][c]
    __shared__ __align__(16) unsigned short s_q[4][64 * 26];  // per-wave Q [n][i] stride 26
    __shared__ float s_l[4][64];

    const int tid = threadIdx.x;
    const int b = blockIdx.x >> 11;
    const int n_base = (blockIdx.x & 2047) << 6;
    const int lane = tid & 63;
    const int wv = tid >> 6;     // head index
    const int lc = lane & 15;
    const int lg = lane >> 4;

    unsigned short* qs = s_q[wv];

    // ---- stage x^T [64][72] cooperatively (R15 verbatim) ----
    {
        int n_l = tid & 63;
        int c0  = (tid >> 6) * 16;
        const float* xb = x + ((size_t)b << 23) + n_base + n_l;
        uint32* xrow = (uint32*)&s_at[n_l * 72 + c0];
#pragma unroll
        for (int r = 0; r < 8; ++r) {
            float v0 = xb[(size_t)(c0 + 2 * r) << 17];
            float v1 = xb[(size_t)(c0 + 2 * r + 1) << 17];
            xrow[r] = cvtpk(v0, v1);
        }
    }
    __syncthreads();   // B1: x^T staged

    // ---- Q-proj (R15 verbatim, store stride 26) ----
#pragma unroll
    for (int t = 0; t < 4; ++t) {
        floatx4 c = {0.f, 0.f, 0.f, 0.f};
#pragma unroll
        for (int ks = 0; ks < 2; ++ks) {
            short8 a  = *(const short8*)&s_at[(t * 16 + lc) * 72 + ks * 32 + lg * 8];
            short8 bb = *(const short8*)(wqb + (wv * 16 + lc) * 64 + ks * 32 + lg * 8);
            c = __builtin_amdgcn_mfma_f32_16x16x32_bf16(a, bb, c, 0, 0, 0);
        }
#pragma unroll
        for (int r = 0; r < 4; ++r)
            qs[(t * 16 + lg * 4 + r) * 26 + lc] = bf16b(c[r]);
    }
    // ---- hoist Q B-frags: logical k=i=lg*4+e via emb4 (memory-fed) ----
    short8 qf[4];
#pragma unroll
    for (int t = 0; t < 4; ++t)
        qf[t] = emb4m(&qs[(t * 16 + lc) * 26 + lg * 4]);

    __syncthreads();   // B2: all Q-proj s_at reads done (att overwrites s_at later)

    // ---- head loop: 16 j-tiles of 16 keys, all-register P (R15 verbatim) ----
    const unsigned short* kh = kt + (((size_t)b * 4 + wv) << 12);
    const unsigned short* vh = vt + (((size_t)b * 4 + wv) << 12);
    float lp[4] = {0.f, 0.f, 0.f, 0.f};
    floatx4 pv[4];
#pragma unroll
    for (int t = 0; t < 4; ++t) pv[t] = {0.f, 0.f, 0.f, 0.f};

#pragma unroll 4
    for (int jt = 0; jt < 16; ++jt) {
        const int j0 = jt * 16;
        short8 kf = emb4m(kh + (size_t)(j0 + lc) * 16 + lg * 4);
        short8 vf = emb4m(vh + (size_t)lc * 256 + j0 + lg * 4);
#pragma unroll
        for (int t = 0; t < 4; ++t) {
            floatx4 z = {0.f, 0.f, 0.f, 0.f};
            floatx4 c = __builtin_amdgcn_mfma_f32_16x16x32_bf16(kf, qf[t], z, 0, 0, 0); // S^T: n=lc, j=lg*4+r
            float p0 = EXP2(c[0]), p1 = EXP2(c[1]), p2 = EXP2(c[2]), p3 = EXP2(c[3]);
            lp[t] += (p0 + p1) + (p2 + p3);
            short8 pa = emb4(pk2(p0, p1), pk2(p2, p3));       // P: row=n=lc, logical k=j=lg*4+e
            pv[t] = __builtin_amdgcn_mfma_f32_16x16x32_bf16(pa, vf, pv[t], 0, 0, 0);    // att: i=lc, n=lg*4+r
        }
    }

    // ---- denominators via s_l (R15 verbatim), rescale, att -> s_at ----
#pragma unroll
    for (int t = 0; t < 4; ++t) {
        lp[t] += __shfl_xor(lp[t], 16, 64);
        lp[t] += __shfl_xor(lp[t], 32, 64);
    }
    if (lane < 16) {
#pragma unroll
        for (int t = 0; t < 4; ++t) s_l[wv][t * 16 + lane] = lp[t];
    }
#pragma unroll
    for (int t = 0; t < 4; ++t) {
#pragma unroll
        for (int r = 0; r < 4; ++r) {
            float rl = RCPF(s_l[wv][t * 16 + lg * 4 + r]);
            s_at[(t * 16 + lg * 4 + r) * 72 + wv * 16 + lc] = bf16b(pv[t][r] * rl);
        }
    }

    __syncthreads();   // B3: att complete

    // ---- out-proj + direct float4 stores (R15 verbatim):
    //      o = wv*16+lc (C col), n = n_base + t*16 + lg*4 + r (C row) ----
#pragma unroll
    for (int t = 0; t < 4; ++t) {
        floatx4 c = {0.f, 0.f, 0.f, 0.f};
#pragma unroll
        for (int ks = 0; ks < 2; ++ks) {
            short8 a  = *(const short8*)&s_at[(t * 16 + lc) * 72 + ks * 32 + lg * 8];
            short8 bb = *(const short8*)(woutb + (wv * 16 + lc) * 64 + ks * 32 + lg * 8);
            c = __builtin_amdgcn_mfma_f32_16x16x32_bf16(a, bb, c, 0, 0, 0);
        }
        float* dst = out + ((size_t)b << 23) + (size_t)(wv * 16 + lc) * NPOS
                   + n_base + t * 16 + lg * 4;
        *(floatx4*)dst = c;
    }
}

extern "C" void kernel_launch(void* const* d_in, const int* in_sizes, int n_in,
                              void* d_out, int out_size, void* d_ws, size_t ws_size,
                              hipStream_t stream) {
    const float* x    = (const float*)d_in[0];
    const float* wq   = (const float*)d_in[1];
    const float* wkv  = (const float*)d_in[2];
    const float* wout = (const float*)d_in[3];
    float* out = (float*)d_out;
    float* ws = (float*)d_ws;

    unsigned short* wtb = (unsigned short*)ws;              // [64][128][512] bf16 = 8 MB
    float* partial = ws + 2097152;                          // [64][2][256][128] f32 = 16 MB
    unsigned short* ktu = (unsigned short*)(ws + 6291456);  // [2][4][256][16] bf16
    unsigned short* vtu   = ktu + 32768;                    // [2][4][16][256] bf16
    unsigned short* wqb   = vtu + 32768;                    // [64][64] bf16
    unsigned short* woutb = wqb + 4096;                     // [64][64] bf16

    k_prep_w   <<<16,   256, 0, stream>>>(wq, wout, wqb, woutb);
    k_prep_wkvb<<<4096, 256, 0, stream>>>(wkv, wtb);
    k_conv_mfma<<<512,  256, 0, stream>>>(x, wtb, partial);
    k_reduce   <<<256,  256, 0, stream>>>(partial, ktu, vtu);
    k_attn12   <<<4096, 256, 0, stream>>>(x, wqb, woutb, ktu, vtu, out);
}

// Round 17
// 100.820 us; speedup vs baseline: 1.0950x; 1.0002x over previous
//
#include <hip/hip_runtime.h>
#include <hip/hip_bf16.h>

#define NPOS 131072   // 32*64*64 positions per batch

typedef __attribute__((ext_vector_type(8))) short short8;
typedef __attribute__((ext_vector_type(4))) float floatx4;
typedef unsigned int uint32;

__device__ __forceinline__ unsigned short bf16b(float v) {
    __hip_bfloat16 h = __float2bfloat16(v);
    return __builtin_bit_cast(unsigned short, h);
}
// inline-asm pack: ONLY for values destined to LDS/global (never straight to MFMA)
__device__ __forceinline__ uint32 cvtpk(float lo, float hi) {
    uint32 r;
    asm("v_cvt_pk_bf16_f32 %0, %1, %2" : "=v"(r) : "v"(lo), "v"(hi));
    return r;
}
// compiler-visible pack: safe to feed MFMA operands (hazards + scheduling handled)
__device__ __forceinline__ uint32 pk2(float lo, float hi) {
    return (uint32)bf16b(lo) | ((uint32)bf16b(hi) << 16);
}
#if __has_builtin(__builtin_amdgcn_exp2f)
#define EXP2(x) __builtin_amdgcn_exp2f(x)
#else
#define EXP2(x) exp2f(x)
#endif
#if __has_builtin(__builtin_amdgcn_rcpf)
#define RCPF(x) __builtin_amdgcn_rcpf(x)
#else
#define RCPF(x) (1.0f / (x))
#endif

// 16x16x32 operand with logical k=lg*4+e at element slots e=0..3, zeros at e=4..7.
__device__ __forceinline__ short8 emb4(uint32 w0, uint32 w1) {
    union { uint32 u[4]; short8 s; } z;
    z.u[0] = w0; z.u[1] = w1; z.u[2] = 0; z.u[3] = 0;
    return z.s;
}
// alias-safe 8-byte load (memcpy => ds_read_b64 / global_load_dwordx2, no TBAA punning)
__device__ __forceinline__ short8 emb4m(const unsigned short* p) {
    uint32 w[2];
    __builtin_memcpy(w, p, 8);
    return emb4(w[0], w[1]);
}

// ---------------- K0: wq -> bf16*QS, wout -> bf16 ----------------
__global__ void k_prep_w(const float* __restrict__ wq, const float* __restrict__ wout,
                         unsigned short* __restrict__ wqb, unsigned short* __restrict__ woutb) {
    const float QS = 0.36067376022224085f;   // 0.25 * log2(e)
    int gid = blockIdx.x * 256 + threadIdx.x;
    wqb[gid]   = bf16b(wq[gid] * QS);
    woutb[gid] = bf16b(wout[gid]);
}

// ---------------- K1: wkv[oc][ic][term] f32 -> wtb[ic][oc][term] bf16 ----------------
__global__ void k_prep_wkvb(const float* __restrict__ wkv, unsigned short* __restrict__ wtb) {
    int gid = blockIdx.x * 256 + threadIdx.x;
    int ic = gid >> 14;
    int oc = (gid >> 7) & 127;
    float4 v = *(const float4*)(wkv + ((size_t)(oc * 64 + ic)) * 512 + (size_t)(gid & 127) * 4);
    uint32* dst = (uint32*)(wtb + (size_t)gid * 4);
    dst[0] = cvtpk(v.x, v.y);
    dst[1] = cvtpk(v.z, v.w);
}

// ---------------- K2: conv as bf16 MFMA GEMM, split-K over ic (R12-exact, passing) ----------------
__global__ __launch_bounds__(256) void k_conv_mfma(const float* __restrict__ x,
                                                   const unsigned short* __restrict__ wtb,
                                                   float* __restrict__ partial) {
    __shared__ __align__(16) unsigned short As[64 * 72];
    __shared__ __align__(16) unsigned short Bs[128 * 72];
    const int bid = blockIdx.x;
    const int ic = bid & 63;
    const int b  = (bid >> 6) & 1;
    const int pz = bid >> 7;
    const int tid = threadIdx.x;
    const int lane = tid & 63, wv = tid >> 6;
    const int lc = lane & 15, lg = lane >> 4;

    floatx4 acc[4][2];
#pragma unroll
    for (int mt = 0; mt < 4; ++mt)
#pragma unroll
        for (int n = 0; n < 2; ++n) acc[mt][n] = {0.f, 0.f, 0.f, 0.f};

    const float* xp = x + ((size_t)b * 64 + ic) * NPOS + (size_t)pz * 8 * 4096;
    const unsigned short* wp = wtb + (size_t)ic * 128 * 512;

    for (int rz = 0; rz < 8; ++rz) {
        __syncthreads();
        const float* plane = xp + (size_t)rz * 4096;
#pragma unroll
        for (int t2 = 0; t2 < 4; ++t2) {
            int e = (t2 * 256 + tid) * 4;
            int y = e >> 6, x0 = e & 63;
            int p = ((y >> 3) << 3) + (x0 >> 3);
            int k = ((y & 7) << 3) + (x0 & 7);
            float4 v = *(const float4*)(plane + e);
            uint32* dst = (uint32*)&As[p * 72 + k];
            dst[0] = cvtpk(v.x, v.y);
            dst[1] = cvtpk(v.z, v.w);
        }
        {
            int oc = tid >> 1, hf = tid & 1;
            const uint4* src = (const uint4*)(wp + (size_t)oc * 512 + rz * 64 + hf * 32);
            uint4* dst = (uint4*)&Bs[oc * 72 + hf * 32];
#pragma unroll
            for (int r = 0; r < 4; ++r) dst[r] = src[r];
        }
        __syncthreads();
#pragma unroll
        for (int ks = 0; ks < 2; ++ks) {
            short8 bb0 = *(const short8*)&Bs[((wv * 2 + 0) * 16 + lc) * 72 + ks * 32 + lg * 8];
            short8 bb1 = *(const short8*)&Bs[((wv * 2 + 1) * 16 + lc) * 72 + ks * 32 + lg * 8];
#pragma unroll
            for (int mt = 0; mt < 4; ++mt) {
                short8 a = *(const short8*)&As[(mt * 16 + lc) * 72 + ks * 32 + lg * 8];
                acc[mt][0] = __builtin_amdgcn_mfma_f32_16x16x32_bf16(a, bb0, acc[mt][0], 0, 0, 0);
                acc[mt][1] = __builtin_amdgcn_mfma_f32_16x16x32_bf16(a, bb1, acc[mt][1], 0, 0, 0);
            }
        }
    }
    float* pb = partial + (((size_t)ic * 2 + b) * 256 + pz * 64) * 128;
#pragma unroll
    for (int mt = 0; mt < 4; ++mt)
#pragma unroll
        for (int ntl = 0; ntl < 2; ++ntl) {
            int oc = (wv * 2 + ntl) * 16 + lc;
#pragma unroll
            for (int r = 0; r < 4; ++r) {
                int m = mt * 16 + lg * 4 + r;
                pb[(size_t)m * 128 + oc] = acc[mt][ntl][r];
            }
        }
}

// ---------------- K3: reduce over ic; K -> bf16 [b][h][256][16], V -> bf16 [b][h][16][256] ----------------
__global__ void k_reduce(const float* __restrict__ partial,
                         unsigned short* __restrict__ kt, unsigned short* __restrict__ vt) {
    int gid = blockIdx.x * 256 + threadIdx.x;
    int oc = gid & 127;
    int bp = gid >> 7;          // b*256 + j
    int b = bp >> 8;
    int j = bp & 255;
    const float* p = partial + (size_t)bp * 128 + oc;
    float s = 0.f;
#pragma unroll 8
    for (int ic = 0; ic < 64; ++ic) s += p[(size_t)ic * 65536];
    int h = (oc & 63) >> 4, i = oc & 15;
    if (oc < 64)
        kt[(((size_t)b * 4 + h) * 256 + j) * 16 + i] = bf16b(s);
    else
        vt[(((size_t)b * 4 + h) * 16 + i) * 256 + j] = bf16b(s);
}

// ---------------- K4: TBAA-safe register-P attention; stride-20 Q; 8 blocks/CU LDS ----------------
// grid 4096 = b(2) x 2048 n-blocks of 64; 256 thr; wave wv = head wv, 64 queries/wave.
// Fix vs R13/R14: Q-frag hoist AFTER barrier B2 (fence orders the transposed LDS
// write->read), and all punned loads via __builtin_memcpy (alias-safe).
__global__ __launch_bounds__(256, 5) void k_attn13(
    const float* __restrict__ x, const unsigned short* __restrict__ wqb,
    const unsigned short* __restrict__ woutb, const unsigned short* __restrict__ kt,
    const unsigned short* __restrict__ vt, float* __restrict__ out)
{
    __shared__ __align__(16) unsigned short s_at[64 * 72];    // x^T then att [n][c]
    __shared__ __align__(16) unsigned short s_q[4][64 * 20];  // per-wave Q [n][i] stride 20
    __shared__ float s_l[4][64];

    const int tid = threadIdx.x;
    const int b = blockIdx.x >> 11;
    const int n_base = (blockIdx.x & 2047) << 6;
    const int lane = tid & 63;
    const int wv = tid >> 6;     // head index
    const int lc = lane & 15;
    const int lg = lane >> 4;

    unsigned short* qs = s_q[wv];

    // ---- stage x^T [64][72] cooperatively (verified pattern) ----
    {
        int n_l = tid & 63;
        int c0  = (tid >> 6) * 16;
        const float* xb = x + ((size_t)b << 23) + n_base + n_l;
        uint32* xrow = (uint32*)&s_at[n_l * 72 + c0];
#pragma unroll
        for (int r = 0; r < 8; ++r) {
            float v0 = xb[(size_t)(c0 + 2 * r) << 17];
            float v1 = xb[(size_t)(c0 + 2 * r + 1) << 17];
            xrow[r] = cvtpk(v0, v1);
        }
    }
    __syncthreads();   // B1: x^T staged

    // ---- Q-proj (verified pattern, store stride 20) ----
#pragma unroll
    for (int t = 0; t < 4; ++t) {
        floatx4 c = {0.f, 0.f, 0.f, 0.f};
#pragma unroll
        for (int ks = 0; ks < 2; ++ks) {
            short8 a  = *(const short8*)&s_at[(t * 16 + lc) * 72 + ks * 32 + lg * 8];
            short8 bb = emb4m(wqb + (wv * 16 + lc) * 64 + ks * 32 + lg * 8),
                   bf = bb;   // placeholder to keep diff minimal (unused)
            (void)bf;
            // full 8-element B fragment (k = ks*32 + lg*8 + e):
            short8 bfull;
            __builtin_memcpy(&bfull, wqb + (wv * 16 + lc) * 64 + ks * 32 + lg * 8, 16);
            c = __builtin_amdgcn_mfma_f32_16x16x32_bf16(a, bfull, c, 0, 0, 0);
        }
#pragma unroll
        for (int r = 0; r < 4; ++r)
            qs[(t * 16 + lg * 4 + r) * 20 + lc] = bf16b(c[r]);
    }

    __syncthreads();   // B2: fences Q writes (cross-lane) AND all Q-proj s_at reads

    // ---- hoist Q B-frags AFTER the barrier: logical k=i=lg*4+e via emb4 ----
    short8 qf[4];
#pragma unroll
    for (int t = 0; t < 4; ++t)
        qf[t] = emb4m(&qs[(t * 16 + lc) * 20 + lg * 4]);

    // ---- head loop: 16 j-tiles of 16 keys, all-register P ----
    const unsigned short* kh = kt + (((size_t)b * 4 + wv) << 12);
    const unsigned short* vh = vt + (((size_t)b * 4 + wv) << 12);
    float lp[4] = {0.f, 0.f, 0.f, 0.f};
    floatx4 pv[4];
#pragma unroll
    for (int t = 0; t < 4; ++t) pv[t] = {0.f, 0.f, 0.f, 0.f};

#pragma unroll 4
    for (int jt = 0; jt < 16; ++jt) {
        const int j0 = jt * 16;
        short8 kf = emb4m(kh + (size_t)(j0 + lc) * 16 + lg * 4);
        short8 vf = emb4m(vh + (size_t)lc * 256 + j0 + lg * 4);
#pragma unroll
        for (int t = 0; t < 4; ++t) {
            floatx4 z = {0.f, 0.f, 0.f, 0.f};
            floatx4 c = __builtin_amdgcn_mfma_f32_16x16x32_bf16(kf, qf[t], z, 0, 0, 0); // S^T: n=lc, j=lg*4+r
            float p0 = EXP2(c[0]), p1 = EXP2(c[1]), p2 = EXP2(c[2]), p3 = EXP2(c[3]);
            lp[t] += (p0 + p1) + (p2 + p3);
            short8 pa = emb4(pk2(p0, p1), pk2(p2, p3));       // P: row=n=lc, logical k=j=lg*4+e
            pv[t] = __builtin_amdgcn_mfma_f32_16x16x32_bf16(pa, vf, pv[t], 0, 0, 0);    // att: i=lc, n=lg*4+r
        }
    }

    // ---- denominators via s_l (verified), rescale, att -> s_at ----
#pragma unroll
    for (int t = 0; t < 4; ++t) {
        lp[t] += __shfl_xor(lp[t], 16, 64);
        lp[t] += __shfl_xor(lp[t], 32, 64);
    }
    if (lane < 16) {
#pragma unroll
        for (int t = 0; t < 4; ++t) s_l[wv][t * 16 + lane] = lp[t];
    }
#pragma unroll
    for (int t = 0; t < 4; ++t) {
#pragma unroll
        for (int r = 0; r < 4; ++r) {
            float rl = RCPF(s_l[wv][t * 16 + lg * 4 + r]);
            s_at[(t * 16 + lg * 4 + r) * 72 + wv * 16 + lc] = bf16b(pv[t][r] * rl);
        }
    }

    __syncthreads();   // B3: att complete (fences transposed att writes -> reads)

    // ---- out-proj + direct float4 stores: o = wv*16+lc (C col), n = C row ----
#pragma unroll
    for (int t = 0; t < 4; ++t) {
        floatx4 c = {0.f, 0.f, 0.f, 0.f};
#pragma unroll
        for (int ks = 0; ks < 2; ++ks) {
            short8 a = *(const short8*)&s_at[(t * 16 + lc) * 72 + ks * 32 + lg * 8];
            short8 bfull;
            __builtin_memcpy(&bfull, woutb + (wv * 16 + lc) * 64 + ks * 32 + lg * 8, 16);
            c = __builtin_amdgcn_mfma_f32_16x16x32_bf16(a, bfull, c, 0, 0, 0);
        }
        float* dst = out + ((size_t)b << 23) + (size_t)(wv * 16 + lc) * NPOS
                   + n_base + t * 16 + lg * 4;
        *(floatx4*)dst = c;
    }
}

extern "C" void kernel_launch(void* const* d_in, const int* in_sizes, int n_in,
                              void* d_out, int out_size, void* d_ws, size_t ws_size,
                              hipStream_t stream) {
    const float* x    = (const float*)d_in[0];
    const float* wq   = (const float*)d_in[1];
    const float* wkv  = (const float*)d_in[2];
    const float* wout = (const float*)d_in[3];
    float* out = (float*)d_out;
    float* ws = (float*)d_ws;

    unsigned short* wtb = (unsigned short*)ws;              // [64][128][512] bf16 = 8 MB
    float* partial = ws + 2097152;                          // [64][2][256][128] f32 = 16 MB
    unsigned short* ktu = (unsigned short*)(ws + 6291456);  // [2][4][256][16] bf16
    unsigned short* vtu   = ktu + 32768;                    // [2][4][16][256] bf16
    unsigned short* wqb   = vtu + 32768;                    // [64][64] bf16
    unsigned short* woutb = wqb + 4096;                     // [64][64] bf16

    k_prep_w   <<<16,   256, 0, stream>>>(wq, wout, wqb, woutb);
    k_prep_wkvb<<<4096, 256, 0, stream>>>(wkv, wtb);
    k_conv_mfma<<<512,  256, 0, stream>>>(x, wtb, partial);
    k_reduce   <<<256,  256, 0, stream>>>(partial, ktu, vtu);
    k_attn13   <<<4096, 256, 0, stream>>>(x, wqb, woutb, ktu, vtu, out);
}